// Round 12
// baseline (128.568 us; speedup 1.0000x reference)
//
#include <hip/hip_runtime.h>
#include <hip/hip_fp16.h>

// y[e, o] = sum_i weight[widx[e]][o][i] * values[iidx[e]][i]
// E = 1e6, N_W = 1024, D_IN = D_OUT = 16, fp32 in/out.
//
// History: R11 direct 81us -> R13 4-wave 73 -> R14 fp16 W 67 -> R15 VMEM
// 132->54 instr 53 -> R16 fp16-x+fdot2 51.5 -> R17 y-staged stores ~46
// (BEST) -> R18/R19/R20 depth-4 attempts null (compiler re-serializes its
// own VMEM; sched_barrier/pins don't hold) -> R21 all-asm VMEM: compile
// fail (HIP float4 = struct -> "indirect register" asm operands).
//
// R22 = R21 with (a) ext_vector_type(4) float for every asm operand
// (HK-style), (b) RE-AUDITED static vmcnt ledger fixing 3 real bugs:
//   - iter-1 under-wait (queue 8, not 12-14: groups 1-3 must be v6)
//   - stores count in vmcnt on CDNA (DRAIN's 4 stores now in ledger)
//   - final-iter tail under-wait (no next-batch issues: v4/v2/v0)
// Verified by tracing ALL entry shapes (prologue=6, steady=12, idx-less=12,
// final): top v6; groups 1-12 v6; groups 13-15 v10 (hasn) / v4,v2,v0.
// Every wait retires the consumed pair in every path. Known cost: ~100cy
// over-force at g1/g13 per batch (vs ~700cy C target).
// W pipeline: depth 4, seamless across batches (g12-15 of batch n issue
// g0-3 + x + idx of n+1/n+2). y double-buffered in LDS, drained at next
// top so stores age ~14 groups before any wait touches them.
// Predicted: VGPR 44 -> 72-100 (depth realized), steady ~46 -> 38-42us
// (total ~115-121), FETCH/WRITE flat, conflicts 0, absmax 0.125.
// Wrong results => ledger bug -> revert R17. Flat at high VGPR => TA
// issue-rate wall, R17 structure was the knee.

#define D 16
#define WPB 4            // waves per block
#define TPB (WPB * 64)
#define MAXBLK 2048

typedef float    f32x4 __attribute__((ext_vector_type(4)));
typedef _Float16 h2v   __attribute__((ext_vector_type(2)));

// ---------------- fallback naive kernel (R1, 137us) ----------------
__global__ __launch_bounds__(256) void linear_gather_mv(
    const float* __restrict__ values, const float* __restrict__ weight,
    const int* __restrict__ input_idx, const int* __restrict__ weight_idx,
    float* __restrict__ out, int E)
{
    int tid = blockIdx.x * blockDim.x + threadIdx.x;
    int e = tid >> 2;
    int j = tid & 3;
    if (e >= E) return;
    int ii = input_idx[e];
    int wi = weight_idx[e];
    const float4* xp = (const float4*)(values + (long long)ii * D);
    float4 x0 = xp[0], x1 = xp[1], x2 = xp[2], x3 = xp[3];
    const float4* wp = (const float4*)(weight + (long long)wi * (D * D) + j * (4 * D));
    float4 acc;
    float* accp = (float*)&acc;
    #pragma unroll
    for (int r = 0; r < 4; ++r) {
        float4 w0 = wp[r * 4 + 0], w1 = wp[r * 4 + 1], w2 = wp[r * 4 + 2], w3 = wp[r * 4 + 3];
        accp[r] = w0.x * x0.x + w0.y * x0.y + w0.z * x0.z + w0.w * x0.w
                + w1.x * x1.x + w1.y * x1.y + w1.z * x1.z + w1.w * x1.w
                + w2.x * x2.x + w2.y * x2.y + w2.z * x2.z + w2.w * x2.w
                + w3.x * x3.x + w3.y * x3.y + w3.z * x3.z + w3.w * x3.w;
    }
    ((float4*)out)[(long long)e * 4 + j] = acc;
}

// ---------------- W fp32 -> fp16 conversion ----------------
__global__ __launch_bounds__(256) void wconv(
    const float* __restrict__ w, __half* __restrict__ wh, int n)
{
    int i = (blockIdx.x * 256 + threadIdx.x) * 4;
    if (i + 3 >= n) {
        for (int k = i; k < n; ++k) wh[k] = __float2half(w[k]);
        return;
    }
    float4 v = *(const float4*)(w + i);
    __half2 a = __floats2half2_rn(v.x, v.y);
    __half2 b = __floats2half2_rn(v.z, v.w);
    float2 packed;
    ((__half2*)&packed)[0] = a;
    ((__half2*)&packed)[1] = b;
    *(float2*)(wh + i) = packed;
}

// ---- asm W group issue: 2 dwordx4 = 2 fp16 matrices each (4 conns) ----
#define WISSUE(WIV, K, W0, W1) do {                                            \
    int a0 = __builtin_amdgcn_readlane(WIV, 4*(K)+0);                          \
    int a1 = __builtin_amdgcn_readlane(WIV, 4*(K)+1);                          \
    int a2 = __builtin_amdgcn_readlane(WIV, 4*(K)+2);                          \
    int a3 = __builtin_amdgcn_readlane(WIV, 4*(K)+3);                          \
    unsigned long long ad0 = wb + ((unsigned long long)(unsigned)(lh ? a1 : a0) << 9); \
    unsigned long long ad1 = wb + ((unsigned long long)(unsigned)(lh ? a3 : a2) << 9); \
    asm volatile("global_load_dwordx4 %0, %2, off\n\t"                         \
                 "global_load_dwordx4 %1, %3, off"                             \
                 : "=&v"(W0), "=&v"(W1)                                        \
                 : "v"(ad0), "v"(ad1) : "memory");                             \
} while (0)

// counted wait, data-pinned to the pair it guards (rule-18-safe)
#define VWAIT(N, W0, W1)                                                       \
    asm volatile("s_waitcnt vmcnt(" #N ")" : "+v"(W0), "+v"(W1))

// One step = 2 conns (CC + lh): one b128 LDS read of fp16 x, 4 fdot2,
// xor-1 reduce, even lanes stage y[c][row] to fp16 LDS.
#define STEP(CC, WV) do {                                                      \
    int c  = (CC) + lh;                                                        \
    f32x4 xv = *(const f32x4*)(xh + (size_t)c * D + (h << 3));                 \
    const h2v* xp2 = (const h2v*)&xv;                                          \
    const h2v* wp2 = (const h2v*)&(WV);                                        \
    float p = __builtin_amdgcn_fdot2(wp2[0], xp2[0], 0.0f, false);             \
    p = __builtin_amdgcn_fdot2(wp2[1], xp2[1], p, false);                      \
    p = __builtin_amdgcn_fdot2(wp2[2], xp2[2], p, false);                      \
    p = __builtin_amdgcn_fdot2(wp2[3], xp2[3], p, false);                      \
    p += __shfl_xor(p, 1);                                                     \
    if (h == 0) yw[c * D + rr] = (_Float16)p;                                  \
} while (0)

#define COMP4(K, W0, W1) do { STEP(4*(K)+0, W0); STEP(4*(K)+2, W1); } while (0)

// asm idx loads (2 dword)
#define IDXA(BI, IV, WV) do {                                                  \
    int kl = (BI) * 64 + lane; if (kl >= E) kl = E - 1;                        \
    unsigned long long ai = (unsigned long long)iidx + ((unsigned)kl << 2);    \
    unsigned long long aw = (unsigned long long)widx + ((unsigned)kl << 2);    \
    asm volatile("global_load_dword %0, %1, off" : "=&v"(IV) : "v"(ai) : "memory"); \
    asm volatile("global_load_dword %0, %1, off" : "=&v"(WV) : "v"(aw) : "memory"); \
} while (0)

// asm x gather (4 dwordx4, 64 random lines in flight)
#define XLOADA(IV) do {                                                        \
    int iiu; unsigned long long ax;                                            \
    iiu = __shfl(IV,      g4); ax = vb + ((unsigned long long)(unsigned)iiu << 6); \
    asm volatile("global_load_dwordx4 %0, %1, off" : "=&v"(xq0) : "v"(ax) : "memory"); \
    iiu = __shfl(IV, 16 + g4); ax = vb + ((unsigned long long)(unsigned)iiu << 6); \
    asm volatile("global_load_dwordx4 %0, %1, off" : "=&v"(xq1) : "v"(ax) : "memory"); \
    iiu = __shfl(IV, 32 + g4); ax = vb + ((unsigned long long)(unsigned)iiu << 6); \
    asm volatile("global_load_dwordx4 %0, %1, off" : "=&v"(xq2) : "v"(ax) : "memory"); \
    iiu = __shfl(IV, 48 + g4); ax = vb + ((unsigned long long)(unsigned)iiu << 6); \
    asm volatile("global_load_dwordx4 %0, %1, off" : "=&v"(xq3) : "v"(ax) : "memory"); \
} while (0)

// commit one fp32 quarter as fp16 (RN): 8B b64 write at conn*32 + q*8
#define COMMIT(U, XQ) do {                                                     \
    __half2 c0 = __floats2half2_rn((XQ).x, (XQ).y);                            \
    __half2 c1 = __floats2half2_rn((XQ).z, (XQ).w);                            \
    float2 pk;                                                                 \
    ((__half2*)&pk)[0] = c0;                                                   \
    ((__half2*)&pk)[1] = c1;                                                   \
    *(float2*)(xh + ((U)*16 + g4) * D + (q << 2)) = pk;                        \
} while (0)

// drain previous batch's y from LDS: 4 asm dwordx4 dense stores
#define DRAIN(YD, PO, PNB) do {                                                \
    _Pragma("unroll")                                                          \
    for (int j = 0; j < 4; ++j) {                                              \
        float2 raw = *(const float2*)((const char*)(YD) + j * 512 + lane * 8); \
        float2 f0 = __half22float2(((const __half2*)&raw)[0]);                 \
        float2 f1 = __half22float2(((const __half2*)&raw)[1]);                 \
        f32x4 o; o.x = f0.x; o.y = f0.y; o.z = f1.x; o.w = f1.y;               \
        int cc = j * 16 + (lane >> 2);                                         \
        if (cc < (PNB)) {                                                      \
            unsigned long long ao = (unsigned long long)(PO)                   \
                                  + (unsigned)(j * 1024 + lane * 16);          \
            asm volatile("global_store_dwordx4 %0, %1, off"                    \
                         :: "v"(ao), "v"(o) : "memory");                       \
        }                                                                      \
    }                                                                          \
} while (0)

__global__ __launch_bounds__(TPB, 4) void direct_mv(
    const float* __restrict__ values, const __half* __restrict__ wh,
    const int* __restrict__ iidx, const int* __restrict__ widx,
    float* __restrict__ out, int E)
{
    __shared__ _Float16 xh_all[WPB * 64 * D];   // 2KB/wave fp16 x
    __shared__ _Float16 yA_all[WPB * 64 * D];   // 2KB/wave y buf A
    __shared__ _Float16 yB_all[WPB * 64 * D];   // 2KB/wave y buf B
    const int lane = threadIdx.x & 63;
    const int wid  = threadIdx.x >> 6;
    _Float16* xh = xh_all + wid * (64 * D);
    _Float16* yA = yA_all + wid * (64 * D);
    _Float16* yB = yB_all + wid * (64 * D);
    const int g4 = lane >> 2;           // gather: conn-in-16
    const int q  = lane & 3;            // gather: quarter
    const int lh   = lane >> 5;         // compute: conn-in-pair
    const int h    = lane & 1;          // compute: row half
    const int hrow = lane & 31;         // compute: float4 idx into 512B mat
    const int rr   = (lane & 31) >> 1;  // compute: output row

    const unsigned long long wb = (unsigned long long)wh + (unsigned)(hrow << 4);
    const unsigned long long vb = (unsigned long long)values + (unsigned)(q << 4);

    const int nbatch = (E + 63) >> 6;
    const int gw = blockIdx.x * WPB + wid;
    const int GW = gridDim.x * WPB;
    if (gw >= nbatch) return;

    int ivC, wvC, ivN, wvN;
    f32x4 xq0, xq1, xq2, xq3;
    f32x4 A0, A1, B0, B1, C0, C1, E0, E1;

    // ---- prologue: queue = [x4, (idxN2), g0..g3] (12 or 14) ----
    IDXA(gw, ivC, wvC);
    asm volatile("s_waitcnt vmcnt(0)" : "+v"(ivC), "+v"(wvC));
    XLOADA(ivC);
    if (gw + GW < nbatch) IDXA(gw + GW, ivN, wvN);
    else { ivN = ivC; wvN = wvC; }
    WISSUE(wvC, 0, A0, A1);
    WISSUE(wvC, 1, B0, B1);
    WISSUE(wvC, 2, C0, C1);
    WISSUE(wvC, 3, E0, E1);
    VWAIT(6, A0, A1);                 // completes x4 (+idxN) + g0

    float* po = nullptr; int pnb = 0;
    _Float16* yw = yA;                // write buffer (this batch's y)
    _Float16* yd = yB;                // drain buffer (previous batch's y)

    for (int bi = gw; bi < nbatch; bi += GW) {
        // TOP v6: steady entry=12 [g0,x4,idx2,g1,g2,g3] (g0 done at prev
        // tail) -> completes x4+idx2, leaves [g1,g2,g3]=6. iter1 entry=6:
        // no-op (x,idx done in prologue). Pins order all consumers.
        asm volatile("s_waitcnt vmcnt(6)"
                     : "+v"(xq0), "+v"(xq1), "+v"(xq2), "+v"(xq3),
                       "+v"(A0), "+v"(A1),
                       "+v"(wvC), "+v"(ivN), "+v"(wvN));
        COMMIT(0, xq0);
        COMMIT(1, xq1);
        COMMIT(2, xq2);
        COMMIT(3, xq3);
        if (po) DRAIN(yd, po, pnb);   // +4 stores (in ledger)
        int k0 = bi * 64;
        int nb = E - k0; if (nb > 64) nb = 64;

        // groups 0-12: uniform v6; every wait retires the consumed pair
        // in iter-1 (queue 8), steady (queue 10-12), and final paths.
        COMP4( 0, A0, A1);                   WISSUE(wvC,  4, A0, A1);
        VWAIT(6, B0, B1); COMP4( 1, B0, B1); WISSUE(wvC,  5, B0, B1);
        VWAIT(6, C0, C1); COMP4( 2, C0, C1); WISSUE(wvC,  6, C0, C1);
        VWAIT(6, E0, E1); COMP4( 3, E0, E1); WISSUE(wvC,  7, E0, E1);
        VWAIT(6, A0, A1); COMP4( 4, A0, A1); WISSUE(wvC,  8, A0, A1);
        VWAIT(6, B0, B1); COMP4( 5, B0, B1); WISSUE(wvC,  9, B0, B1);
        VWAIT(6, C0, C1); COMP4( 6, C0, C1); WISSUE(wvC, 10, C0, C1);
        VWAIT(6, E0, E1); COMP4( 7, E0, E1); WISSUE(wvC, 11, E0, E1);
        VWAIT(6, A0, A1); COMP4( 8, A0, A1); WISSUE(wvC, 12, A0, A1);
        VWAIT(6, B0, B1); COMP4( 9, B0, B1); WISSUE(wvC, 13, B0, B1);
        VWAIT(6, C0, C1); COMP4(10, C0, C1); WISSUE(wvC, 14, C0, C1);
        VWAIT(6, E0, E1); COMP4(11, E0, E1); WISSUE(wvC, 15, E0, E1);
        VWAIT(6, A0, A1); COMP4(12, A0, A1);

        int bn = bi + GW;
        if (bn < nbatch) {
            // seamless: issue next batch g0 + x + idx(n+2) here
            WISSUE(wvN, 0, A0, A1);
            XLOADA(ivN);
            int bn2 = bi + 2 * GW;
            if (bn2 < nbatch) IDXA(bn2, ivC, wvC);
            // v10 safe with AND without the idx issue (min of 12/10)
            VWAIT(10, B0, B1); COMP4(13, B0, B1); WISSUE(wvN, 1, B0, B1);
            VWAIT(10, C0, C1); COMP4(14, C0, C1); WISSUE(wvN, 2, C0, C1);
            VWAIT(10, E0, E1); COMP4(15, E0, E1); WISSUE(wvN, 3, E0, E1);
        } else {
            // final iteration: queue is only [g13,g14,g15]=6
            VWAIT(4, B0, B1); COMP4(13, B0, B1);
            VWAIT(2, C0, C1); COMP4(14, C0, C1);
            VWAIT(0, E0, E1); COMP4(15, E0, E1);
        }

        po = out + (long long)k0 * D; pnb = nb;
        int t;
        t = ivC; ivC = ivN; ivN = t;
        t = wvC; wvC = wvN; wvN = t;
        _Float16* ty = yw; yw = yd; yd = ty;
    }

    // epilogue: drain the last batch's y
    if (po) DRAIN(yd, po, pnb);
}

extern "C" void kernel_launch(void* const* d_in, const int* in_sizes, int n_in,
                              void* d_out, int out_size, void* d_ws, size_t ws_size,
                              hipStream_t stream) {
    const float* values     = (const float*)d_in[0];
    const float* weight     = (const float*)d_in[1];
    const int*   input_idx  = (const int*)d_in[2];
    const int*   weight_idx = (const int*)d_in[3];
    float*       out        = (float*)d_out;

    int E = in_sizes[2];
    if (E <= 0) return;
    int NW = in_sizes[1] / (D * D);
    size_t need = (size_t)NW * D * D * sizeof(__half);

    if (ws_size < need) {
        int total_thr = E * 4;
        int grid = (total_thr + 255) / 256;
        hipLaunchKernelGGL(linear_gather_mv, dim3(grid), dim3(256), 0, stream,
                           values, weight, input_idx, weight_idx, out, E);
        return;
    }

    __half* wh = (__half*)d_ws;
    int nconv = NW * D * D;
    int cblk = (nconv / 4 + 255) / 256;
    hipLaunchKernelGGL(wconv, dim3(cblk), dim3(256), 0, stream,
                       weight, wh, nconv);

    int nbatch = (E + 63) >> 6;
    int nblk = (nbatch + WPB - 1) / WPB;
    if (nblk > MAXBLK) nblk = MAXBLK;
    hipLaunchKernelGGL(direct_mv, dim3(nblk), dim3(TPB), 0, stream,
                       values, wh, input_idx, weight_idx, out, E);
}